// Round 4
// baseline (320.151 us; speedup 1.0000x reference)
//
#include <hip/hip_runtime.h>
#include <hip/hip_fp16.h>

// ScaledDotProductAttention: context = softmax(QK^T/sqrt(d) - 100*mask) @ V
// B=32 Tq=2048 Tk=1024 d=128 dv=256, fp32 in/out.
// R4: single-pass (traffic-optimal) with kBQ=32 so LDS = exactly 80 KB ->
// TWO independent workgroups per CU (independent barrier domains decouple the
// lockstep that kept R1/R3 at ~1.5 TB/s). rowsum lives in the K region after
// phase 1 (dead space) to stay within the 81920-byte budget.

namespace {

constexpr int kB = 32, kTq = 2048, kTk = 1024, kD = 128, kDv = 256;
constexpr int kBQ  = 32;   // q rows per workgroup
constexpr int kBK  = 64;   // key tile (QK^T)
constexpr int kBK2 = 32;   // key tile (PV)
constexpr float kScale = 0.08838834764831845f;  // 1/sqrt(128)

typedef _Float16 half8 __attribute__((ext_vector_type(8)));
typedef _Float16 half4 __attribute__((ext_vector_type(4)));
typedef float    f32x4 __attribute__((ext_vector_type(4)));

// LDS map (bytes) — total EXACTLY 81920 so 2 wgs/CU co-reside (160 KiB / 2).
constexpr int kOffP = 0;        // P [32 q][1024 k] fp16 swizzled   (65536)
constexpr int kOffK = 65536;    // K tile [64 k][128 d] f16 swz     (16384)
                                //  = V^T [256 dv][32 k] f16 swz  (phase 4)
                                //  = rowsum[32] f32               (phase 2/3)
constexpr int kLds  = 81920;

__device__ __forceinline__ int pswz(int row, int cb) {  // row<32, cb<2048
  return kOffP + row * 2048 + (cb ^ ((row & 7) << 4));
}
__device__ __forceinline__ int kswz(int row, int cb) {  // row<64, cb<256
  return kOffK + row * 256 + (cb ^ ((row & 7) << 4));
}
__device__ __forceinline__ int vswz(int dv, int kb) {   // dv<256, kb<64
  return kOffK + dv * 64 + (kb ^ ((dv & 3) << 4));
}

__global__ __launch_bounds__(512, 4)
void attn_fused(const float* __restrict__ qg, const float* __restrict__ kg,
                const float* __restrict__ vg, const float* __restrict__ mg,
                float* __restrict__ out) {
  __shared__ __align__(16) unsigned char s_[kLds];

  const int tid  = threadIdx.x;
  const int lane = tid & 63;
  const int wid  = tid >> 6;     // 0..7
  const int l15  = lane & 15;
  const int lg   = lane >> 4;    // 0..3

  // XCD-friendly mapping: all 64 q-blocks of a batch land on one XCD
  const int bi    = blockIdx.x;               // 0..2047
  const int batch = (bi & 7) * 4 + (bi >> 9); // fixed per (bi&7, bi>>9)
  const int q0    = ((bi >> 3) & 63) * kBQ;

  const float* Q = qg + ((size_t)batch * kTq + q0) * kD;
  const float* K = kg + (size_t)batch * kTk * kD;
  const float* V = vg + (size_t)batch * kTk * kDv;
  const float* M = mg + ((size_t)batch * kTq + q0) * kTk;
  float* CTX = out + ((size_t)batch * kTq + q0) * kDv;
  float* SCR = out + (size_t)kB * kTq * kDv + ((size_t)batch * kTq + q0) * kTk;

  // wave tiling: wave owns 16 q rows x 16 keys (QK^T) / 16 q x 64 dv (PV)
  const int wr = wid >> 2;   // 0..1 : q row group
  const int wc = wid & 3;    // 0..3 : col group

  // ---- Q fragments (16 rows x 128 d per wave) ----
  half8 qf[4];
  {
    const float* qrow = Q + (size_t)(wr * 16 + l15) * kD + lg * 8;
#pragma unroll
    for (int c = 0; c < 4; ++c) {
      f32x4 a = *(const f32x4*)(qrow + c * 32);
      f32x4 b = *(const f32x4*)(qrow + c * 32 + 4);
      half8 h;
      h[0] = a[0]; h[1] = a[1]; h[2] = a[2]; h[3] = a[3];
      h[4] = b[0]; h[5] = b[1]; h[6] = b[2]; h[7] = b[3];
      qf[c] = h;
    }
  }

  // ================= Phase 1: S=QK^T, e=exp -> P(LDS), rowsums =================
  const int srow = tid >> 3;          // 0..63 (K staging row)
  const int scol = (tid & 7) * 16;    // float col (16 floats per thread)
  f32x4 st[4];
#pragma unroll
  for (int s = 0; s < 4; ++s)
    st[s] = *(const f32x4*)(K + (size_t)srow * kD + scol + s * 4);

  float mv[4], mvN[4];
#pragma unroll
  for (int j = 0; j < 4; ++j)
    mv[j] = M[(size_t)(wr * 16 + lg * 4 + j) * kTk + wc * 16 + l15];

  float rsum[4] = {0.f, 0.f, 0.f, 0.f};
  constexpr int kSteps = kTk / kBK;   // 16
  for (int step = 0; step < kSteps; ++step) {
    __syncthreads();                  // prior K-tile reads done
    {
      half8 h0, h1;
#pragma unroll
      for (int e = 0; e < 4; ++e) { h0[e] = st[0][e]; h0[4 + e] = st[1][e];
                                    h1[e] = st[2][e]; h1[4 + e] = st[3][e]; }
      *(half8*)(s_ + kswz(srow, scol * 2))      = h0;
      *(half8*)(s_ + kswz(srow, scol * 2 + 16)) = h1;
    }
    __syncthreads();
    if (step + 1 < kSteps) {          // prefetch next K tile + next mask
      const float* Kn = K + (size_t)(step + 1) * kBK * kD;
#pragma unroll
      for (int s = 0; s < 4; ++s)
        st[s] = *(const f32x4*)(Kn + (size_t)srow * kD + scol + s * 4);
#pragma unroll
      for (int j = 0; j < 4; ++j)
        mvN[j] = M[(size_t)(wr * 16 + lg * 4 + j) * kTk +
                   (step + 1) * kBK + wc * 16 + l15];
    }
    f32x4 acc = {0.f, 0.f, 0.f, 0.f};
    __builtin_amdgcn_s_setprio(1);
#pragma unroll
    for (int c = 0; c < 4; ++c) {
      half8 bf = *(const half8*)(s_ + kswz(wc * 16 + l15, c * 64 + lg * 16));
      acc = __builtin_amdgcn_mfma_f32_16x16x32_f16(qf[c], bf, acc, 0, 0, 0);
    }
    __builtin_amdgcn_s_setprio(0);
#pragma unroll
    for (int j = 0; j < 4; ++j) {
      float e = __expf(acc[j] * kScale - 100.f * mv[j]);
      rsum[j] += e;
      *(_Float16*)(s_ + pswz(wr * 16 + lg * 4 + j,
                             (step * kBK + wc * 16 + l15) * 2)) = (_Float16)e;
    }
#pragma unroll
    for (int j = 0; j < 4; ++j) mv[j] = mvN[j];
  }

  // ================= Phase 2: rowsums (in dead K region) ================
  __syncthreads();                    // all K reads done -> region reusable
  float* rowsum = (float*)(s_ + kOffK);
  if (tid < kBQ) rowsum[tid] = 0.f;
  __syncthreads();
#pragma unroll
  for (int m = 1; m <= 8; m <<= 1)
#pragma unroll
    for (int j = 0; j < 4; ++j) rsum[j] += __shfl_xor(rsum[j], m);
  if (l15 == 0) {
#pragma unroll
    for (int j = 0; j < 4; ++j)
      atomicAdd(&rowsum[wr * 16 + lg * 4 + j], rsum[j]);
  }
  __syncthreads();
  if (tid < kBQ) rowsum[tid] = 1.0f / rowsum[tid];
  __syncthreads();
  float invr[4];
#pragma unroll
  for (int j = 0; j < 4; ++j) invr[j] = rowsum[wr * 16 + lg * 4 + j];

  // ---- V tile-0 loads issued early (fly over the score writes) ----
  const int vcol = tid & 255;   // dv column
  const int vkh  = tid >> 8;    // key octet 0..1
  float vst[16];
#pragma unroll
  for (int j = 0; j < 16; ++j)
    vst[j] = V[(size_t)(vkh * 16 + j) * kDv + vcol];

  // ================= Phase 3: normalized score write (coalesced f32x4) ========
#pragma unroll
  for (int rr = 0; rr < 4; ++rr) {
    int row = wid * 4 + rr;
    float inv = rowsum[row];
#pragma unroll
    for (int it = 0; it < 4; ++it) {
      int col = it * 256 + lane * 4;
      half4 hv = *(const half4*)(s_ + pswz(row, col * 2));
      f32x4 o;
      o[0] = (float)hv[0] * inv; o[1] = (float)hv[1] * inv;
      o[2] = (float)hv[2] * inv; o[3] = (float)hv[3] * inv;
      *(f32x4*)(SCR + (size_t)row * kTk + col) = o;
    }
  }

  // ================= Phase 4: context = (P @ V) * inv =================
  f32x4 acc4[4];
#pragma unroll
  for (int t = 0; t < 4; ++t) acc4[t] = (f32x4){0, 0, 0, 0};

  constexpr int kSteps4 = kTk / kBK2;   // 32
  for (int step = 0; step < kSteps4; ++step) {
    __syncthreads();   // V^T region free (1st iter: rowsum reads all done)
    {
      half8 h0, h1;
#pragma unroll
      for (int j = 0; j < 8; ++j) { h0[j] = vst[j]; h1[j] = vst[8 + j]; }
      *(half8*)(s_ + vswz(vcol, vkh * 32))      = h0;
      *(half8*)(s_ + vswz(vcol, vkh * 32 + 16)) = h1;
    }
    __syncthreads();
    if (step + 1 < kSteps4) {           // prefetch next V tile over the MFMAs
      const float* Vn = V + (size_t)(step + 1) * kBK2 * kDv;
#pragma unroll
      for (int j = 0; j < 16; ++j)
        vst[j] = Vn[(size_t)(vkh * 16 + j) * kDv + vcol];
    }
    int arow = wr * 16 + l15;
    half8 af = *(const half8*)(s_ + pswz(arow, step * 64 + lg * 16));
    __builtin_amdgcn_s_setprio(1);
#pragma unroll
    for (int t = 0; t < 4; ++t) {
      half8 bf = *(const half8*)(s_ + vswz(wc * 64 + t * 16 + l15, lg * 16));
      acc4[t] = __builtin_amdgcn_mfma_f32_16x16x32_f16(af, bf, acc4[t], 0, 0, 0);
    }
    __builtin_amdgcn_s_setprio(0);
  }

  // epilogue: scale by 1/rowsum (captured in invr), store context
#pragma unroll
  for (int t = 0; t < 4; ++t)
#pragma unroll
    for (int j = 0; j < 4; ++j)
      CTX[(size_t)(wr * 16 + lg * 4 + j) * kDv + wc * 64 + t * 16 + l15] =
          acc4[t][j] * invr[j];
}

}  // namespace

extern "C" void kernel_launch(void* const* d_in, const int* in_sizes, int n_in,
                              void* d_out, int out_size, void* d_ws, size_t ws_size,
                              hipStream_t stream) {
  const float* q = (const float*)d_in[0];
  const float* k = (const float*)d_in[1];
  const float* v = (const float*)d_in[2];
  const float* m = (const float*)d_in[3];
  float* out = (float*)d_out;
  (void)in_sizes; (void)n_in; (void)out_size; (void)d_ws; (void)ws_size;

  dim3 grid(kB * (kTq / kBQ));   // 2048 workgroups
  dim3 block(512);
  hipLaunchKernelGGL(attn_fused, grid, block, 0, stream, q, k, v, m, out);
}